// Round 1
// 444.551 us; speedup vs baseline: 1.0370x; 1.0370x over previous
//
#include <hip/hip_runtime.h>

#define SEQ 2048
#define BATCH 16
#define DMODEL 512
#define FFDIM 2048
#define NTOK (SEQ * BATCH) /* 32768 tokens */
#define ALPHA 0.9f

typedef unsigned short u16;
typedef __attribute__((ext_vector_type(8))) short short8;
typedef __attribute__((ext_vector_type(4))) float f32x4;

__device__ __forceinline__ float bf2f(u16 u) {
    unsigned int v = ((unsigned int)u) << 16;
    return __builtin_bit_cast(float, v);
}
__device__ __forceinline__ u16 f2bf(float f) {
    unsigned int v = __builtin_bit_cast(unsigned int, f);
    v += 0x7fffu + ((v >> 16) & 1u);   // RNE
    return (u16)(v >> 16);
}

// ---------------------------------------------------------------------------
// fp32 -> bf16 conversion (weights), 4 elems/thread
// ---------------------------------------------------------------------------
__global__ __launch_bounds__(256) void cvt_kernel(const float* __restrict__ in,
                                                  u16* __restrict__ out, int n) {
    const int i = (blockIdx.x * 256 + threadIdx.x) * 4;
    if (i >= n) return;
    float4 v = *(const float4*)(in + i);
    ushort4 o;
    o.x = f2bf(v.x); o.y = f2bf(v.y); o.z = f2bf(v.z); o.w = f2bf(v.w);
    *(ushort4*)(out + i) = o;
}

// ---------------------------------------------------------------------------
// LayerNorm: one wave per token (64 lanes x 8 elems = 512 = DMODEL)
// fp32 in, bf16 out; fp32 gamma/beta
// ---------------------------------------------------------------------------
__global__ __launch_bounds__(256) void ln_kernel(const float* __restrict__ xin,
                                                 const float* __restrict__ g,
                                                 const float* __restrict__ b,
                                                 u16* __restrict__ y) {
    const int lane = threadIdx.x & 63;
    const int wave = threadIdx.x >> 6;
    const long tok = (long)blockIdx.x * 4 + wave;
    const long off = tok * DMODEL + lane * 8;

    float f[8];
    {
        const float4* xp = (const float4*)(xin + off);
        float4 a = xp[0], c = xp[1];
        f[0] = a.x; f[1] = a.y; f[2] = a.z; f[3] = a.w;
        f[4] = c.x; f[5] = c.y; f[6] = c.z; f[7] = c.w;
    }
    float s = 0.f, s2 = 0.f;
#pragma unroll
    for (int i = 0; i < 8; i++) { s += f[i]; s2 += f[i] * f[i]; }
#pragma unroll
    for (int o = 32; o > 0; o >>= 1) {
        s += __shfl_xor(s, o, 64);
        s2 += __shfl_xor(s2, o, 64);
    }
    const float mean = s * (1.f / DMODEL);
    const float var = s2 * (1.f / DMODEL) - mean * mean;
    const float inv = rsqrtf(var + 1e-5f);

    const float4* gp = (const float4*)(g + lane * 8);
    const float4* bp = (const float4*)(b + lane * 8);
    float4 g0 = gp[0], g1 = gp[1], b0 = bp[0], b1 = bp[1];
    float gg[8] = {g0.x, g0.y, g0.z, g0.w, g1.x, g1.y, g1.z, g1.w};
    float bb[8] = {b0.x, b0.y, b0.z, b0.w, b1.x, b1.y, b1.z, b1.w};
    short8 ov;
#pragma unroll
    for (int i = 0; i < 8; i++)
        ov[i] = (short)f2bf((f[i] - mean) * inv * gg[i] + bb[i]);
    *(short8*)(y + off) = ov;
}

// ---------------------------------------------------------------------------
// Causal exp-decay mixing as a scan (unchanged)
// ---------------------------------------------------------------------------
#define SCAN_L 128
#define SCAN_H 160
__global__ __launch_bounds__(256) void scan_kernel(const u16* __restrict__ z,
                                                   const float* __restrict__ x,
                                                   float* __restrict__ x1) {
    const int p = blockIdx.x * 256 + threadIdx.x;  // 0..8191  (b*512+d)
    const int s0 = blockIdx.y * SCAN_L;
    int s = s0 - SCAN_H;
    if (s < 0) s = 0;
    float r = 0.f;
    for (; s < s0; ++s)
        r = ALPHA * (bf2f(z[(long)s * 8192 + p]) + r);

    float ap = powf(ALPHA, (float)(s0 + 2));  // alpha^{s0+2}
#pragma unroll 4
    for (int i = 0; i < SCAN_L; i++) {
        const long idx = (long)(s0 + i) * 8192 + p;
        const float zf = bf2f(z[idx]);
        r = ALPHA * (zf + r);
        const float c = 1.f - (ALPHA - ap) * 10.f;  // 10 = 1/(1-alpha)
        x1[idx] = x[idx] + r + c * zf;
        ap *= ALPHA;
    }
}

// ---------------------------------------------------------------------------
// GEMM 256x256 / BK=64 / 8 waves, T1+T2+T3+T4+T5 stack:
//   C[M,N] = epi(A[M,K] @ Bt[N,K]^T + bias[N])
// - LDS: double-buffered A/B K-tiles, 128 KiB, octet-XOR swizzle (T2) applied
//   on the *global source* of global_load_lds (dest stays linear) and on the
//   ds_read addresses (rule #21: both-sides-or-neither).
// - Pipeline: stage tile t+1 at head of body t (8 gld_lds/thread), then
//   s_waitcnt vmcnt(8): tile t landed, tile t+1 stays in flight across all of
//   body t's barriers (T4 counted, never vmcnt(0) mid-loop). Slot is provably
//   dead: last reader finished before previous body's final barrier.
// - 4 phases/tile (16 MFMA = 2 M-frags x 4 N-frags x 2 kk), raw s_barrier
//   pairs + s_setprio(1) around the MFMA cluster (T5).
// EPI: 0=+bias  1=relu(+bias)  2=+bias+resid(fp32);  OUT_F32 selects store type
// ---------------------------------------------------------------------------
#define BM 256
#define BN 256
#define BKK 64

typedef __attribute__((address_space(1))) unsigned int as1_u32;
typedef __attribute__((address_space(3))) unsigned int as3_u32;

__device__ __forceinline__ void gld_lds16(const void* g, const void* l) {
    __builtin_amdgcn_global_load_lds((as1_u32*)(unsigned long long)g,
                                     (as3_u32*)(unsigned int)(unsigned long long)l,
                                     16, 0, 0);
}

template <int EPI, bool OUT_F32>
__global__ __launch_bounds__(512, 2) void gemm256(const u16* __restrict__ A,
                                                  const u16* __restrict__ Bt,
                                                  const float* __restrict__ bias,
                                                  const float* __restrict__ resid,
                                                  void* __restrict__ C,
                                                  int M, int N, int K) {
    __shared__ alignas(16) u16 sA[2][BM * BKK];
    __shared__ alignas(16) u16 sB[2][BN * BKK];

    const int tid = threadIdx.x;
    const int lane = tid & 63;
    const int wave = tid >> 6;
    const int wr = wave >> 2;      // 0..1 -> 128-row panel
    const int wc = wave & 3;       // 0..3 -> 64-col panel
    const int l15 = lane & 15, q16 = lane >> 4;

    // T1: bijective XCD swizzle (all launches have nwg % 8 == 0)
    const int gx = gridDim.x;
    const int nwg = gx * gridDim.y;
    const int lin = blockIdx.y * gx + blockIdx.x;
    const int cpx = nwg >> 3;
    const int swz = (lin & 7) * cpx + (lin >> 3);
    const int m0 = (swz % gx) * BM;
    const int n0 = (swz / gx) * BN;

    // ---- staging addresses: chunk ch = tid + 512*i, LDS linear, source
    //      octet pre-swizzled: oo = (ch&7) ^ (row&7)  (T2, rule #21) ----
    const u16* gA[4];
    const u16* gB[4];
    int ldsoff[4];
#pragma unroll
    for (int i = 0; i < 4; i++) {
        const int ch = tid + i * 512;           // 0..2047
        const int r = ch >> 3;                  // row 0..255
        const int oo = (ch & 7) ^ (r & 7);      // swizzled source octet
        gA[i] = A + (long)(m0 + r) * K + oo * 8;
        gB[i] = Bt + (long)(n0 + r) * K + oo * 8;
        ldsoff[i] = ch * 8;                     // u16 elements
    }

    // ---- fragment read addressing (swizzled): elem = row*64 + ((kk*4+q16)^ (row&7))*8
    //      row&7 == l15&7 for every fragment row (offsets are multiples of 16) ----
    const int x7 = l15 & 7;
    int octk[2];
    octk[0] = ((0 + q16) ^ x7) * 8;
    octk[1] = ((4 + q16) ^ x7) * 8;
    const int rowA0 = wr * 128 + l15;
    const int rowB0 = wc * 64 + l15;

    f32x4 acc[8][4];
#pragma unroll
    for (int i = 0; i < 8; i++)
#pragma unroll
        for (int j = 0; j < 4; j++) acc[i][j] = (f32x4){0.f, 0.f, 0.f, 0.f};

    const int NT = K / BKK;

    // prologue: stage tile 0 -> buf 0
#pragma unroll
    for (int i = 0; i < 4; i++) gld_lds16(gA[i], &sA[0][ldsoff[i]]);
#pragma unroll
    for (int i = 0; i < 4; i++) gld_lds16(gB[i], &sB[0][ldsoff[i]]);

#pragma unroll 1
    for (int t = 0; t < NT; ++t) {
        const int pb = t & 1;
        // ---- boundary: stage t+1 (into the buffer last read in body t-1),
        //      then counted wait for tile t ----
        if (t + 1 < NT) {
            const int pn = (t + 1) & 1;
            const int ko = (t + 1) * BKK;
#pragma unroll
            for (int i = 0; i < 4; i++) gld_lds16(gA[i] + ko, &sA[pn][ldsoff[i]]);
#pragma unroll
            for (int i = 0; i < 4; i++) gld_lds16(gB[i] + ko, &sB[pn][ldsoff[i]]);
            asm volatile("s_waitcnt vmcnt(8)" ::: "memory");
        } else {
            asm volatile("s_waitcnt vmcnt(0)" ::: "memory");
        }
        __builtin_amdgcn_s_barrier();

        const u16* pa = &sA[pb][rowA0 * BKK];
        const u16* pbb = &sB[pb][rowB0 * BKK];

        // B-panel fragments for the whole tile (8 x ds_read_b128)
        short8 bf[4][2];
#pragma unroll
        for (int nj = 0; nj < 4; nj++)
#pragma unroll
            for (int kk = 0; kk < 2; kk++)
                bf[nj][kk] = *(const short8*)(pbb + nj * 16 * BKK + octk[kk]);

        // 4 phases: quadrant m2 -> A frags (4 reads) + 16 MFMA under setprio
#pragma unroll
        for (int m2 = 0; m2 < 4; m2++) {
            short8 af[2][2];
#pragma unroll
            for (int mi = 0; mi < 2; mi++)
#pragma unroll
                for (int kk = 0; kk < 2; kk++)
                    af[mi][kk] = *(const short8*)(pa + (m2 * 32 + mi * 16) * BKK + octk[kk]);
            __builtin_amdgcn_s_barrier();
            __builtin_amdgcn_s_setprio(1);
#pragma unroll
            for (int mi = 0; mi < 2; mi++)
#pragma unroll
                for (int nj = 0; nj < 4; nj++)
#pragma unroll
                    for (int kk = 0; kk < 2; kk++)
                        acc[m2 * 2 + mi][nj] = __builtin_amdgcn_mfma_f32_16x16x32_bf16(
                            af[mi][kk], bf[nj][kk], acc[m2 * 2 + mi][nj], 0, 0, 0);
            __builtin_amdgcn_s_setprio(0);
            __builtin_amdgcn_s_barrier();
        }
    }

    // ---- epilogue: C/D layout col=lane&15, row=(lane>>4)*4+reg ----
#pragma unroll
    for (int mf = 0; mf < 8; mf++) {
        const int row = m0 + wr * 128 + mf * 16 + q16 * 4;
#pragma unroll
        for (int nj = 0; nj < 4; nj++) {
            const int col = n0 + wc * 64 + nj * 16 + l15;
            const float bv = bias[col];
#pragma unroll
            for (int r = 0; r < 4; r++) {
                const long idx = (long)(row + r) * N + col;
                float v = acc[mf][nj][r] + bv;
                if (EPI == 1) v = fmaxf(v, 0.f);
                if (EPI == 2) v += resid[idx];
                if (OUT_F32)
                    ((float*)C)[idx] = v;
                else
                    ((u16*)C)[idx] = f2bf(v);
            }
        }
    }
}

// ---------------------------------------------------------------------------
extern "C" void kernel_launch(void* const* d_in, const int* in_sizes, int n_in,
                              void* d_out, int out_size, void* d_ws, size_t ws_size,
                              hipStream_t stream) {
    const float* x = (const float*)d_in[0];
    const float* w_lin = (const float*)d_in[1];
    const float* b_lin = (const float*)d_in[2];
    const float* w1 = (const float*)d_in[3];
    const float* b1 = (const float*)d_in[4];
    const float* w2 = (const float*)d_in[5];
    const float* b2 = (const float*)d_in[6];
    const float* g1 = (const float*)d_in[7];
    const float* be1 = (const float*)d_in[8];
    const float* g2 = (const float*)d_in[9];
    const float* be2 = (const float*)d_in[10];
    float* out = (float*)d_out;

    char* ws = (char*)d_ws;
    const size_t MB = 1024 * 1024;
    u16* y = (u16*)(ws);                       // LN output bf16, 32 MB
    float* x1 = (float*)(ws + 32 * MB);        // attn residual fp32, 64 MB
    u16* h = (u16*)(ws + 96 * MB);             // FF hidden bf16, 128 MB
    u16* z = h;                                // projection bf16, 32 MB (aliases h; z dies before h is written)
    u16* wb_lin = (u16*)(ws + 224 * MB);       // bf16 weights
    u16* wb1 = (u16*)(ws + 225 * MB);
    u16* wb2 = (u16*)(ws + 228 * MB);

    // 0) convert weights fp32 -> bf16
    cvt_kernel<<<(DMODEL * DMODEL) / 1024, 256, 0, stream>>>(w_lin, wb_lin, DMODEL * DMODEL);
    cvt_kernel<<<(FFDIM * DMODEL) / 1024, 256, 0, stream>>>(w1, wb1, FFDIM * DMODEL);
    cvt_kernel<<<(DMODEL * FFDIM) / 1024, 256, 0, stream>>>(w2, wb2, DMODEL * FFDIM);

    // 1) y = LN(x; g1, be1)
    ln_kernel<<<NTOK / 4, 256, 0, stream>>>(x, g1, be1, y);
    // 2) z = y @ w_lin^T + b_lin
    gemm256<0, false><<<dim3(NTOK / BM, DMODEL / BN), 512, 0, stream>>>(y, wb_lin, b_lin, nullptr,
                                                                       z, NTOK, DMODEL, DMODEL);
    // 3) x1 = x + W @ z   (exp-decay scan)
    scan_kernel<<<dim3(BATCH * DMODEL / 256, SEQ / SCAN_L), 256, 0, stream>>>(z, x, x1);
    // 4) y = LN(x1; g2, be2)
    ln_kernel<<<NTOK / 4, 256, 0, stream>>>(x1, g2, be2, y);
    // 5) h = relu(y @ w1^T + b1)
    gemm256<1, false><<<dim3(NTOK / BM, FFDIM / BN), 512, 0, stream>>>(y, wb1, b1, nullptr, h,
                                                                      NTOK, FFDIM, DMODEL);
    // 6) out = x1 + h @ w2^T + b2
    gemm256<2, true><<<dim3(NTOK / BM, DMODEL / BN), 512, 0, stream>>>(h, wb2, b2, x1, out,
                                                                      NTOK, DMODEL, FFDIM);
}